// Round 1
// baseline (436.472 us; speedup 1.0000x reference)
//
#include <hip/hip_runtime.h>
#include <hip/hip_bf16.h>

// SparseLinear as dense bf16 MFMA GEMM:
//   out[b,o] = sum_i x[b,i] * W[o,i]   (C = A * B^T, both K-contiguous)
// M=8192 (batch), N=4096 (out), K=4096 (in). bias is dead in the reference.

typedef short bf16x8 __attribute__((ext_vector_type(8)));
typedef float f32x4 __attribute__((ext_vector_type(4)));
typedef unsigned short u16x8 __attribute__((ext_vector_type(8)));

static constexpr int M_DIM = 8192;
static constexpr int N_DIM = 4096;
static constexpr int K_DIM = 4096;
static constexpr int BM = 128, BN = 128, BK = 64;

// RNE f32 -> bf16 (inputs are finite randn values; NaN path not needed)
__device__ __forceinline__ unsigned short f2bf(float f) {
  unsigned int u = __builtin_bit_cast(unsigned int, f);
  u += 0x7fffu + ((u >> 16) & 1u);
  return (unsigned short)(u >> 16);
}

__global__ void cvt_f32_bf16(const float* __restrict__ in,
                             unsigned short* __restrict__ out, long n8) {
  long i = (long)blockIdx.x * blockDim.x + threadIdx.x;
  const long stride = (long)gridDim.x * blockDim.x;
  for (; i < n8; i += stride) {
    f32x4 a = ((const f32x4*)in)[2 * i];
    f32x4 b = ((const f32x4*)in)[2 * i + 1];
    u16x8 v;
    v[0] = f2bf(a[0]); v[1] = f2bf(a[1]); v[2] = f2bf(a[2]); v[3] = f2bf(a[3]);
    v[4] = f2bf(b[0]); v[5] = f2bf(b[1]); v[6] = f2bf(b[2]); v[7] = f2bf(b[3]);
    ((u16x8*)out)[i] = v;
  }
}

// PATH 0: bf16 sources in ws, global_load_lds width-16 staging (m97 structure)
// PATH 1: f32 sources, reg-staged convert->ds_write fallback (no ws needed)
template <int PATH>
__global__ __launch_bounds__(256) void gemm_bt(
    const unsigned short* __restrict__ Ab, const unsigned short* __restrict__ Bb,
    const float* __restrict__ Af, const float* __restrict__ Bf,
    float* __restrict__ C) {
  __shared__ unsigned short sA[BM * BK];  // 16 KB, linear (global_load_lds needs linear)
  __shared__ unsigned short sB[BN * BK];  // 16 KB

  const int tid = threadIdx.x;
  const int lane = tid & 63;
  const int wid = tid >> 6;       // 4 waves, 2x2 wave grid
  const int wr = wid >> 1;
  const int wc = wid & 1;

  // XCD-aware bijective swizzle; grid = 64*32 = 2048, divisible by 8.
  const int nwg = gridDim.x;
  const int cpx = nwg >> 3;
  const int b0 = blockIdx.x;
  const int swz = (b0 & 7) * cpx + (b0 >> 3);
  const int NT = N_DIM / BN;      // 32
  const int row0 = (swz / NT) * BM;
  const int col0 = (swz % NT) * BN;

  f32x4 acc[4][4] = {};

  const int fbase = tid * 8;  // flat bf16 index within a 128x64 tile (pass 0)

  for (int kt = 0; kt < K_DIM; kt += BK) {
    if constexpr (PATH == 0) {
#pragma unroll
      for (int p = 0; p < 4; ++p) {
        const int f = fbase + p * 2048;
        const int r = f >> 6;          // tile row
        const int kc = f & 63;         // k within tile
        const unsigned short* gA = Ab + (size_t)(row0 + r) * K_DIM + kt + kc;
        const unsigned short* gB = Bb + (size_t)(col0 + r) * K_DIM + kt + kc;
        // wave-uniform LDS base; HW adds lane*16B (linear layout matches f)
        unsigned short* lA = sA + wid * 512 + p * 2048;
        unsigned short* lB = sB + wid * 512 + p * 2048;
        __builtin_amdgcn_global_load_lds(
            (const __attribute__((address_space(1))) void*)gA,
            (__attribute__((address_space(3))) void*)lA, 16, 0, 0);
        __builtin_amdgcn_global_load_lds(
            (const __attribute__((address_space(1))) void*)gB,
            (__attribute__((address_space(3))) void*)lB, 16, 0, 0);
      }
    } else {
#pragma unroll
      for (int p = 0; p < 4; ++p) {
        const int f = fbase + p * 2048;
        const int r = f >> 6;
        const int kc = f & 63;
        const float* gA = Af + (size_t)(row0 + r) * K_DIM + kt + kc;
        const float* gB = Bf + (size_t)(col0 + r) * K_DIM + kt + kc;
        f32x4 a0 = ((const f32x4*)gA)[0];
        f32x4 a1 = ((const f32x4*)gA)[1];
        f32x4 c0 = ((const f32x4*)gB)[0];
        f32x4 c1 = ((const f32x4*)gB)[1];
        u16x8 va, vb;
        va[0] = f2bf(a0[0]); va[1] = f2bf(a0[1]); va[2] = f2bf(a0[2]); va[3] = f2bf(a0[3]);
        va[4] = f2bf(a1[0]); va[5] = f2bf(a1[1]); va[6] = f2bf(a1[2]); va[7] = f2bf(a1[3]);
        vb[0] = f2bf(c0[0]); vb[1] = f2bf(c0[1]); vb[2] = f2bf(c0[2]); vb[3] = f2bf(c0[3]);
        vb[4] = f2bf(c1[0]); vb[5] = f2bf(c1[1]); vb[6] = f2bf(c1[2]); vb[7] = f2bf(c1[3]);
        *(u16x8*)&sA[f] = va;
        *(u16x8*)&sB[f] = vb;
      }
    }
    __syncthreads();

#pragma unroll
    for (int kk = 0; kk < 2; ++kk) {
      bf16x8 a[4], b[4];
#pragma unroll
      for (int m = 0; m < 4; ++m)
        a[m] = *(const bf16x8*)&sA[(wr * 64 + m * 16 + (lane & 15)) * BK +
                                   kk * 32 + (lane >> 4) * 8];
#pragma unroll
      for (int n = 0; n < 4; ++n)
        b[n] = *(const bf16x8*)&sB[(wc * 64 + n * 16 + (lane & 15)) * BK +
                                   kk * 32 + (lane >> 4) * 8];
#pragma unroll
      for (int m = 0; m < 4; ++m)
#pragma unroll
        for (int n = 0; n < 4; ++n)
          acc[m][n] =
              __builtin_amdgcn_mfma_f32_16x16x32_bf16(a[m], b[n], acc[m][n], 0, 0, 0);
    }
    __syncthreads();
  }

  // C/D layout (m89-verified): col = lane&15, row = (lane>>4)*4 + j
#pragma unroll
  for (int m = 0; m < 4; ++m) {
#pragma unroll
    for (int n = 0; n < 4; ++n) {
      const int gr = row0 + wr * 64 + m * 16 + (lane >> 4) * 4;
      const int gc = col0 + wc * 64 + n * 16 + (lane & 15);
      float* cp = C + (size_t)gr * N_DIM + gc;
#pragma unroll
      for (int j = 0; j < 4; ++j) cp[(size_t)j * N_DIM] = acc[m][n][j];
    }
  }
}

extern "C" void kernel_launch(void* const* d_in, const int* in_sizes, int n_in,
                              void* d_out, int out_size, void* d_ws, size_t ws_size,
                              hipStream_t stream) {
  const float* x = (const float*)d_in[0];  // [8192, 4096]
  const float* W = (const float*)d_in[1];  // [4096, 4096]
  // d_in[2] = bias: dead in the reference (overwritten before use)
  float* out = (float*)d_out;              // [8192, 4096] f32

  const size_t xb_bytes = (size_t)M_DIM * K_DIM * 2;  // 64 MiB
  const size_t wb_bytes = (size_t)N_DIM * K_DIM * 2;  // 32 MiB

  const dim3 gblk(256);
  const dim3 ggrid((M_DIM / BM) * (N_DIM / BN));  // 2048 blocks

  if (ws_size >= xb_bytes + wb_bytes) {
    unsigned short* Xb = (unsigned short*)d_ws;
    unsigned short* Wb = (unsigned short*)((char*)d_ws + xb_bytes);
    cvt_f32_bf16<<<2048, 256, 0, stream>>>(x, Xb, (long)M_DIM * K_DIM / 8);
    cvt_f32_bf16<<<2048, 256, 0, stream>>>(W, Wb, (long)N_DIM * K_DIM / 8);
    gemm_bt<0><<<ggrid, gblk, 0, stream>>>(Xb, Wb, nullptr, nullptr, out);
  } else {
    gemm_bt<1><<<ggrid, gblk, 0, stream>>>(nullptr, nullptr, x, W, out);
  }
}

// Round 2
// 285.893 us; speedup vs baseline: 1.5267x; 1.5267x over previous
//
#include <hip/hip_runtime.h>
#include <hip/hip_bf16.h>

// SparseLinear as dense bf16 MFMA GEMM: out[b,o] = sum_i x[b,i]*W[o,i]
// C = A * B^T, M=8192, N=4096, K=4096. bias is dead in the reference.
// Structure: 256x256 tile, BK=64, 8 waves, 8-phase counted-vmcnt schedule
// (T1 XCD swizzle + T2 LDS XOR swizzle + T3/T4 8-phase + T5 setprio).

typedef short bf16x8 __attribute__((ext_vector_type(8)));
typedef float f32x4 __attribute__((ext_vector_type(4)));
typedef unsigned short u16x8 __attribute__((ext_vector_type(8)));

static constexpr int M_DIM = 8192;
static constexpr int N_DIM = 4096;
static constexpr int K_DIM = 4096;
static constexpr int BM = 256, BN = 256, BK = 64;
static constexpr int KT = K_DIM / BK;  // 64 K-tiles

__device__ __forceinline__ unsigned short f2bf(float f) {
  unsigned int u = __builtin_bit_cast(unsigned int, f);
  u += 0x7fffu + ((u >> 16) & 1u);
  return (unsigned short)(u >> 16);
}

__global__ void cvt_f32_bf16(const float* __restrict__ in,
                             unsigned short* __restrict__ out, long n8) {
  long i = (long)blockIdx.x * blockDim.x + threadIdx.x;
  const long stride = (long)gridDim.x * blockDim.x;
  for (; i < n8; i += stride) {
    f32x4 a = ((const f32x4*)in)[2 * i];
    f32x4 b = ((const f32x4*)in)[2 * i + 1];
    u16x8 v;
    v[0] = f2bf(a[0]); v[1] = f2bf(a[1]); v[2] = f2bf(a[2]); v[3] = f2bf(a[3]);
    v[4] = f2bf(b[0]); v[5] = f2bf(b[1]); v[6] = f2bf(b[2]); v[7] = f2bf(b[3]);
    ((u16x8*)out)[i] = v;
  }
}

// ---- 8-phase GEMM helpers -------------------------------------------------
// LDS part = 256 rows x 32 k bf16 = 16 KB, row stride 64 B.
// Swizzle (T2, involution): byte ^= ((byte>>7)&3)<<4  (slot ^= (row>>1)&3).
// Spreads 16 same-column rows uniformly over 8 bank-groups (2-way = free).

__device__ __forceinline__ bf16x8 lds_frag(const unsigned short* part, int row,
                                           int ks16 /* (lane>>4)*16 bytes */) {
  int lo = row * 64 + ks16;
  int sw = lo ^ (((lo >> 7) & 3) << 4);
  return *(const bf16x8*)((const char*)part + sw);
}

struct StageIdx { int row0, in0, row1, in1; };

// Linear LDS dest (gload_lds requirement) + pre-swizzled global source:
// lane's 16B lands at linear q; logical offset there = q ^ swz(q).
__device__ __forceinline__ void stage_part(unsigned short* part,
                                           const unsigned short* gbase,
                                           int rowbase, int kbase, int wid,
                                           const StageIdx& s) {
  const unsigned short* g0 = gbase + (size_t)(rowbase + s.row0) * K_DIM + kbase + s.in0;
  const unsigned short* g1 = gbase + (size_t)(rowbase + s.row1) * K_DIM + kbase + s.in1;
  __builtin_amdgcn_global_load_lds(
      (const __attribute__((address_space(1))) void*)g0,
      (__attribute__((address_space(3))) void*)(part + wid * 512), 16, 0, 0);
  __builtin_amdgcn_global_load_lds(
      (const __attribute__((address_space(1))) void*)g1,
      (__attribute__((address_space(3))) void*)(part + wid * 512 + 4096), 16, 0, 0);
}

#define PHASE_MID()                                       \
  __builtin_amdgcn_sched_barrier(0);                      \
  __builtin_amdgcn_s_barrier();                           \
  asm volatile("s_waitcnt lgkmcnt(0)" ::: "memory");      \
  __builtin_amdgcn_sched_barrier(0);                      \
  __builtin_amdgcn_s_setprio(1);

#define PHASE_END()                                       \
  __builtin_amdgcn_s_setprio(0);                          \
  __builtin_amdgcn_sched_barrier(0);                      \
  __builtin_amdgcn_s_barrier();

__global__ __launch_bounds__(512, 2) void gemm8p(
    const unsigned short* __restrict__ Ab, const unsigned short* __restrict__ Bb,
    float* __restrict__ C) {
  // parts: 0 = B,k0..31  1 = A,k0..31  2 = B,k32..63  3 = A,k32..63
  __shared__ unsigned short lds[2][4][8192];  // 128 KiB

  const int tid = threadIdx.x;
  const int lane = tid & 63;
  const int wid = tid >> 6;    // 8 waves
  const int wr = wid >> 2;     // 0..1  (M half: 128 rows)
  const int wc = wid & 3;      // 0..3  (N quarter: 64 cols)
  const int l15 = lane & 15;
  const int ks16 = (lane >> 4) << 4;

  // T1: XCD-aware bijective swizzle (512 blocks, 512 % 8 == 0)
  const int b0i = blockIdx.x;
  const int swz = (b0i & 7) * ((int)gridDim.x >> 3) + (b0i >> 3);
  const int row0 = (swz / (N_DIM / BN)) * BM;
  const int col0 = (swz % (N_DIM / BN)) * BN;

  // per-thread staging indices (constants; inverse-swizzled source)
  StageIdx si;
  {
    int q0 = tid * 16;
    int lo0 = q0 ^ (((q0 >> 7) & 3) << 4);
    si.row0 = lo0 >> 6; si.in0 = (lo0 & 63) >> 1;
    int q1 = tid * 16 + 8192;
    int lo1 = q1 ^ (((q1 >> 7) & 3) << 4);
    si.row1 = lo1 >> 6; si.in1 = (lo1 & 63) >> 1;
  }

  f32x4 acc[8][4] = {};

  // prologue: tile0 all 4 parts (buf0) + tile1 first 3 parts (buf1) = 14 loads
  stage_part(lds[0][0], Bb, col0, 0,  wid, si);
  stage_part(lds[0][1], Ab, row0, 0,  wid, si);
  stage_part(lds[0][2], Bb, col0, 32, wid, si);
  stage_part(lds[0][3], Ab, row0, 32, wid, si);
  stage_part(lds[1][0], Bb, col0, 64, wid, si);
  stage_part(lds[1][1], Ab, row0, 64, wid, si);
  stage_part(lds[1][2], Bb, col0, 96, wid, si);
  asm volatile("s_waitcnt vmcnt(6)" ::: "memory");  // tile0's 8 loads landed
  __builtin_amdgcn_sched_barrier(0);
  __builtin_amdgcn_s_barrier();

  bf16x8 av[4], b0v[4], b1v[4];

#pragma unroll 1
  for (int t = 0; t < KT; ++t) {
    unsigned short(*L)[8192] = lds[t & 1];
    unsigned short(*Ln)[8192] = lds[(t & 1) ^ 1];

    // ---- phase 1: MFMA m0-3 x kk0. reads a[0-3]k0 (part1) + b[0-3]k0 (part0)
    //      stage A-k1 of tile t+1 -> other buf part3 (prev tile's A-k1: consumed)
#pragma unroll
    for (int m = 0; m < 4; ++m) av[m] = lds_frag(L[1], wr * 128 + m * 16 + l15, ks16);
#pragma unroll
    for (int n = 0; n < 4; ++n) b0v[n] = lds_frag(L[0], wc * 64 + n * 16 + l15, ks16);
    if (t < KT - 1) stage_part(Ln[3], Ab, row0, (t + 1) * 64 + 32, wid, si);
    PHASE_MID();
#pragma unroll
    for (int m = 0; m < 4; ++m)
#pragma unroll
      for (int n = 0; n < 4; ++n)
        acc[m][n] = __builtin_amdgcn_mfma_f32_16x16x32_bf16(av[m], b0v[n], acc[m][n], 0, 0, 0);
    PHASE_END();

    // ---- phase 2: MFMA m4-7 x kk0. reads a[4-7]k0 (part1)
    //      stage B-k0 of tile t+2 -> cur part0 (b k0 reads finished phase 1)
#pragma unroll
    for (int m = 0; m < 4; ++m) av[m] = lds_frag(L[1], wr * 128 + (m + 4) * 16 + l15, ks16);
    if (t < KT - 2) stage_part(L[0], Bb, col0, (t + 2) * 64, wid, si);
    PHASE_MID();
#pragma unroll
    for (int m = 0; m < 4; ++m)
#pragma unroll
      for (int n = 0; n < 4; ++n)
        acc[m + 4][n] = __builtin_amdgcn_mfma_f32_16x16x32_bf16(av[m], b0v[n], acc[m + 4][n], 0, 0, 0);
    PHASE_END();

    // ---- phase 3: MFMA m0-3 x kk1. reads a[0-3]k1 (part3) + b[0-3]k1 (part2)
    //      stage A-k0 of tile t+2 -> cur part1 (a k0 reads finished phase 2)
#pragma unroll
    for (int m = 0; m < 4; ++m) av[m] = lds_frag(L[3], wr * 128 + m * 16 + l15, ks16);
#pragma unroll
    for (int n = 0; n < 4; ++n) b1v[n] = lds_frag(L[2], wc * 64 + n * 16 + l15, ks16);
    if (t < KT - 2) stage_part(L[1], Ab, row0, (t + 2) * 64, wid, si);
    PHASE_MID();
#pragma unroll
    for (int m = 0; m < 4; ++m)
#pragma unroll
      for (int n = 0; n < 4; ++n)
        acc[m][n] = __builtin_amdgcn_mfma_f32_16x16x32_bf16(av[m], b1v[n], acc[m][n], 0, 0, 0);
    PHASE_END();

    // ---- phase 4: MFMA m4-7 x kk1. reads a[4-7]k1 (part3)
    //      stage B-k1 of tile t+2 -> cur part2 (b k1 reads finished phase 3)
#pragma unroll
    for (int m = 0; m < 4; ++m) av[m] = lds_frag(L[3], wr * 128 + (m + 4) * 16 + l15, ks16);
    if (t < KT - 2) stage_part(L[2], Bb, col0, (t + 2) * 64 + 32, wid, si);
    PHASE_MID();
#pragma unroll
    for (int m = 0; m < 4; ++m)
#pragma unroll
      for (int n = 0; n < 4; ++n)
        acc[m + 4][n] = __builtin_amdgcn_mfma_f32_16x16x32_bf16(av[m], b1v[n], acc[m + 4][n], 0, 0, 0);
    __builtin_amdgcn_s_setprio(0);
    // counted vmcnt once per K-tile (never 0 in steady state): 3 half-tiles
    // (6 loads) stay in flight; guarantees tile t+1 fully landed.
    if (t < KT - 2) {
      asm volatile("s_waitcnt vmcnt(6)" ::: "memory");
    } else if (t == KT - 2) {
      asm volatile("s_waitcnt vmcnt(0)" ::: "memory");  // drain for last tile
    }
    __builtin_amdgcn_sched_barrier(0);
    __builtin_amdgcn_s_barrier();
  }

  // epilogue: C/D layout col=lane&15, row=(lane>>4)*4+j (m89-verified)
#pragma unroll
  for (int mm = 0; mm < 8; ++mm) {
#pragma unroll
    for (int n = 0; n < 4; ++n) {
      const int gr = row0 + wr * 128 + mm * 16 + (lane >> 4) * 4;
      const int gc = col0 + wc * 64 + n * 16 + l15;
      float* cp = C + (size_t)gr * N_DIM + gc;
#pragma unroll
      for (int j = 0; j < 4; ++j) cp[(size_t)j * N_DIM] = acc[mm][n][j];
    }
  }
}

// ---- fallback (ws too small): round-1 reg-staged f32->bf16 kernel ----------
__global__ __launch_bounds__(256) void gemm_fb(const float* __restrict__ Af,
                                               const float* __restrict__ Bf,
                                               float* __restrict__ C) {
  __shared__ unsigned short sA[128 * 64];
  __shared__ unsigned short sB[128 * 64];
  const int tid = threadIdx.x;
  const int lane = tid & 63;
  const int wid = tid >> 6;
  const int wr = wid >> 1, wc = wid & 1;
  const int cpx = (int)gridDim.x >> 3;
  const int swz = ((int)blockIdx.x & 7) * cpx + ((int)blockIdx.x >> 3);
  const int row0 = (swz / (N_DIM / 128)) * 128;
  const int col0 = (swz % (N_DIM / 128)) * 128;
  f32x4 acc[4][4] = {};
  const int fbase = tid * 8;
  for (int kt = 0; kt < K_DIM; kt += 64) {
#pragma unroll
    for (int p = 0; p < 4; ++p) {
      const int f = fbase + p * 2048;
      const int r = f >> 6, kc = f & 63;
      const float* gA = Af + (size_t)(row0 + r) * K_DIM + kt + kc;
      const float* gB = Bf + (size_t)(col0 + r) * K_DIM + kt + kc;
      f32x4 a0 = ((const f32x4*)gA)[0], a1 = ((const f32x4*)gA)[1];
      f32x4 c0 = ((const f32x4*)gB)[0], c1 = ((const f32x4*)gB)[1];
      u16x8 va, vb;
      va[0] = f2bf(a0[0]); va[1] = f2bf(a0[1]); va[2] = f2bf(a0[2]); va[3] = f2bf(a0[3]);
      va[4] = f2bf(a1[0]); va[5] = f2bf(a1[1]); va[6] = f2bf(a1[2]); va[7] = f2bf(a1[3]);
      vb[0] = f2bf(c0[0]); vb[1] = f2bf(c0[1]); vb[2] = f2bf(c0[2]); vb[3] = f2bf(c0[3]);
      vb[4] = f2bf(c1[0]); vb[5] = f2bf(c1[1]); vb[6] = f2bf(c1[2]); vb[7] = f2bf(c1[3]);
      *(u16x8*)&sA[f] = va;
      *(u16x8*)&sB[f] = vb;
    }
    __syncthreads();
#pragma unroll
    for (int kk = 0; kk < 2; ++kk) {
      bf16x8 a[4], b[4];
#pragma unroll
      for (int m = 0; m < 4; ++m)
        a[m] = *(const bf16x8*)&sA[(wr * 64 + m * 16 + (lane & 15)) * 64 + kk * 32 + (lane >> 4) * 8];
#pragma unroll
      for (int n = 0; n < 4; ++n)
        b[n] = *(const bf16x8*)&sB[(wc * 64 + n * 16 + (lane & 15)) * 64 + kk * 32 + (lane >> 4) * 8];
#pragma unroll
      for (int m = 0; m < 4; ++m)
#pragma unroll
        for (int n = 0; n < 4; ++n)
          acc[m][n] = __builtin_amdgcn_mfma_f32_16x16x32_bf16(a[m], b[n], acc[m][n], 0, 0, 0);
    }
    __syncthreads();
  }
#pragma unroll
  for (int m = 0; m < 4; ++m)
#pragma unroll
    for (int n = 0; n < 4; ++n) {
      const int gr = row0 + wr * 64 + m * 16 + (lane >> 4) * 4;
      const int gc = col0 + wc * 64 + n * 16 + (lane & 15);
      float* cp = C + (size_t)gr * N_DIM + gc;
#pragma unroll
      for (int j = 0; j < 4; ++j) cp[(size_t)j * N_DIM] = acc[m][n][j];
    }
}

extern "C" void kernel_launch(void* const* d_in, const int* in_sizes, int n_in,
                              void* d_out, int out_size, void* d_ws, size_t ws_size,
                              hipStream_t stream) {
  const float* x = (const float*)d_in[0];  // [8192, 4096]
  const float* W = (const float*)d_in[1];  // [4096, 4096]
  float* out = (float*)d_out;              // [8192, 4096] f32

  const size_t xb_bytes = (size_t)M_DIM * K_DIM * 2;  // 64 MiB
  const size_t wb_bytes = (size_t)N_DIM * K_DIM * 2;  // 32 MiB

  if (ws_size >= xb_bytes + wb_bytes) {
    unsigned short* Xb = (unsigned short*)d_ws;
    unsigned short* Wb = (unsigned short*)((char*)d_ws + xb_bytes);
    cvt_f32_bf16<<<2048, 256, 0, stream>>>(x, Xb, (long)M_DIM * K_DIM / 8);
    cvt_f32_bf16<<<2048, 256, 0, stream>>>(W, Wb, (long)N_DIM * K_DIM / 8);
    const dim3 grid((M_DIM / BM) * (N_DIM / BN));  // 512 blocks
    gemm8p<<<grid, dim3(512), 0, stream>>>(Xb, Wb, out);
  } else {
    gemm_fb<<<dim3(2048), dim3(256), 0, stream>>>(x, W, out);
  }
}

// Round 3
// 279.830 us; speedup vs baseline: 1.5598x; 1.0217x over previous
//
#include <hip/hip_runtime.h>
#include <hip/hip_bf16.h>

// SparseLinear as dense bf16 MFMA GEMM: out[b,o] = sum_i x[b,i]*W[o,i]
// C = A * B^T, M=8192, N=4096, K=4096. bias is dead in the reference.
// 256x256 tile, BK=64, 8 waves, 8-phase counted-vmcnt schedule
// (T1 XCD swizzle + T2 LDS XOR swizzle + T3/T4 + T5 setprio).
// R3: slimmed issue path — precomputed swizzled LDS offsets (imm ds_read),
// precomputed stage pointers, minimal fences (lgkm-hint pin + rule-18 only).

typedef short bf16x8 __attribute__((ext_vector_type(8)));
typedef float f32x4 __attribute__((ext_vector_type(4)));
typedef unsigned short u16x8 __attribute__((ext_vector_type(8)));

static constexpr int M_DIM = 8192;
static constexpr int N_DIM = 4096;
static constexpr int K_DIM = 4096;
static constexpr int BM = 256, BN = 256, BK = 64;
static constexpr int KT = K_DIM / BK;  // 64 K-tiles

__device__ __forceinline__ unsigned short f2bf(float f) {
  unsigned int u = __builtin_bit_cast(unsigned int, f);
  u += 0x7fffu + ((u >> 16) & 1u);
  return (unsigned short)(u >> 16);
}

__global__ void cvt_f32_bf16(const float* __restrict__ in,
                             unsigned short* __restrict__ out, long n8) {
  long i = (long)blockIdx.x * blockDim.x + threadIdx.x;
  const long stride = (long)gridDim.x * blockDim.x;
  for (; i < n8; i += stride) {
    f32x4 a = ((const f32x4*)in)[2 * i];
    f32x4 b = ((const f32x4*)in)[2 * i + 1];
    u16x8 v;
    v[0] = f2bf(a[0]); v[1] = f2bf(a[1]); v[2] = f2bf(a[2]); v[3] = f2bf(a[3]);
    v[4] = f2bf(b[0]); v[5] = f2bf(b[1]); v[6] = f2bf(b[2]); v[7] = f2bf(b[3]);
    ((u16x8*)out)[i] = v;
  }
}

// LDS part = 256 rows x 32 k bf16 = 16 KB, row stride 64 B.
// Swizzle (T2, involution): byte ^= ((byte>>7)&3)<<4. XOR bits 4-5 depend
// only on row bits 1-2 (= lane bits 1-2) -> m*1024 / part*16384 offsets are
// swizzle-invariant and fold into the ds_read immediate.

// parts: 0 = B,k0..31  1 = A,k0..31  2 = B,k32..63  3 = A,k32..63
#define PART_B0 0
#define PART_A0 16384
#define PART_B1 32768
#define PART_A1 49152

__device__ __forceinline__ void stage2(const unsigned short* p0,
                                       const unsigned short* p1, int k,
                                       unsigned short* dst) {
  __builtin_amdgcn_global_load_lds(
      (const __attribute__((address_space(1))) void*)(p0 + k),
      (__attribute__((address_space(3))) void*)dst, 16, 0, 0);
  __builtin_amdgcn_global_load_lds(
      (const __attribute__((address_space(1))) void*)(p1 + k),
      (__attribute__((address_space(3))) void*)(dst + 4096), 16, 0, 0);
}

// phase-MID: pin reads/stages pre-barrier (memory clobber) + pre-drain hint,
// then barrier, full LDS wait, rule-18 fence, setprio.
#define PHASE_MID(N)                                              \
  asm volatile("s_waitcnt lgkmcnt(" #N ")" ::: "memory");         \
  __builtin_amdgcn_s_barrier();                                   \
  asm volatile("s_waitcnt lgkmcnt(0)" ::: "memory");              \
  __builtin_amdgcn_sched_barrier(0);                              \
  __builtin_amdgcn_s_setprio(1);

#define PHASE_END()                                               \
  __builtin_amdgcn_s_setprio(0);                                  \
  __builtin_amdgcn_s_barrier();

__global__ __launch_bounds__(512, 2) void gemm8p(
    const unsigned short* __restrict__ Ab, const unsigned short* __restrict__ Bb,
    float* __restrict__ C) {
  __shared__ unsigned short lds[2][4][8192];  // 128 KiB

  const int tid = threadIdx.x;
  const int lane = tid & 63;
  const int wid = tid >> 6;    // 8 waves
  const int wr = wid >> 2;     // 0..1  (M half: 128 rows)
  const int wc = wid & 3;      // 0..3  (N quarter: 64 cols)
  const int l15 = lane & 15;
  const int ks16 = (lane >> 4) << 4;

  // T1: XCD-aware bijective swizzle (512 blocks, 512 % 8 == 0)
  const int b0i = blockIdx.x;
  const int swz = (b0i & 7) * ((int)gridDim.x >> 3) + (b0i >> 3);
  const int row0 = (swz / (N_DIM / BN)) * BM;
  const int col0 = (swz % (N_DIM / BN)) * BN;

  // staging: per-thread inverse-swizzled source indices -> fixed pointers
  int r0, i0, r1, i1;
  {
    int q0 = tid * 16;
    int lo0 = q0 ^ (((q0 >> 7) & 3) << 4);
    r0 = lo0 >> 6; i0 = (lo0 & 63) >> 1;
    int q1 = tid * 16 + 8192;
    int lo1 = q1 ^ (((q1 >> 7) & 3) << 4);
    r1 = lo1 >> 6; i1 = (lo1 & 63) >> 1;
  }
  const unsigned short* pA0 = Ab + (size_t)(row0 + r0) * K_DIM + i0;
  const unsigned short* pA1 = Ab + (size_t)(row0 + r1) * K_DIM + i1;
  const unsigned short* pB0 = Bb + (size_t)(col0 + r0) * K_DIM + i0;
  const unsigned short* pB1 = Bb + (size_t)(col0 + r1) * K_DIM + i1;
  unsigned short* dst0 = &lds[0][0][0] + wid * 512;  // + part offset per use
  unsigned short* dst1 = &lds[1][0][0] + wid * 512;

  // LDS read base offsets (bytes, swizzled; m/n/part folds into immediates)
  int ao = ((wr * 128 + l15) * 64) + ks16;
  ao ^= ((ao >> 7) & 3) << 4;
  int bo = ((wc * 64 + l15) * 64) + ks16;
  bo ^= ((bo >> 7) & 3) << 4;

  f32x4 acc[8][4] = {};

  // prologue: tile0 all 4 parts (buf0) + tile1 first 3 parts (buf1)
  stage2(pB0, pB1, 0, dst0 + 0 * 8192);
  stage2(pA0, pA1, 0, dst0 + 1 * 8192);
  stage2(pB0, pB1, 32, dst0 + 2 * 8192);
  stage2(pA0, pA1, 32, dst0 + 3 * 8192);
  stage2(pB0, pB1, 64, dst1 + 0 * 8192);
  stage2(pA0, pA1, 64, dst1 + 1 * 8192);
  stage2(pB0, pB1, 96, dst1 + 2 * 8192);
  asm volatile("s_waitcnt vmcnt(6)" ::: "memory");  // tile0's 8 loads landed
  __builtin_amdgcn_s_barrier();

  bf16x8 av[4], b0v[4], b1v[4];

#pragma unroll 1
  for (int t = 0; t < KT; ++t) {
    const char* base = (const char*)((t & 1) ? &lds[1][0][0] : &lds[0][0][0]);
    unsigned short* dcur = (t & 1) ? dst1 : dst0;
    unsigned short* dnxt = (t & 1) ? dst0 : dst1;
    const char* bA = base + ao;
    const char* bB = base + bo;

    // ---- phase 1: MFMA m0-3 x kk0 (reads A-k0, B-k0; stage A-k1(t+1)->other)
#pragma unroll
    for (int m = 0; m < 4; ++m) av[m] = *(const bf16x8*)(bA + PART_A0 + m * 1024);
#pragma unroll
    for (int n = 0; n < 4; ++n) b0v[n] = *(const bf16x8*)(bB + PART_B0 + n * 1024);
    if (t < KT - 1) stage2(pA0, pA1, (t + 1) * 64 + 32, dnxt + 3 * 8192);
    PHASE_MID(4)
#pragma unroll
    for (int m = 0; m < 4; ++m)
#pragma unroll
      for (int n = 0; n < 4; ++n)
        acc[m][n] = __builtin_amdgcn_mfma_f32_16x16x32_bf16(av[m], b0v[n], acc[m][n], 0, 0, 0);
    PHASE_END()

    // ---- phase 2: MFMA m4-7 x kk0 (reads A-k0 hi; stage B-k0(t+2)->cur)
#pragma unroll
    for (int m = 0; m < 4; ++m) av[m] = *(const bf16x8*)(bA + PART_A0 + (m + 4) * 1024);
    if (t < KT - 2) stage2(pB0, pB1, (t + 2) * 64, dcur + 0 * 8192);
    PHASE_MID(2)
#pragma unroll
    for (int m = 0; m < 4; ++m)
#pragma unroll
      for (int n = 0; n < 4; ++n)
        acc[m + 4][n] = __builtin_amdgcn_mfma_f32_16x16x32_bf16(av[m], b0v[n], acc[m + 4][n], 0, 0, 0);
    PHASE_END()

    // ---- phase 3: MFMA m0-3 x kk1 (reads A-k1, B-k1; stage A-k0(t+2)->cur)
#pragma unroll
    for (int m = 0; m < 4; ++m) av[m] = *(const bf16x8*)(bA + PART_A1 + m * 1024);
#pragma unroll
    for (int n = 0; n < 4; ++n) b1v[n] = *(const bf16x8*)(bB + PART_B1 + n * 1024);
    if (t < KT - 2) stage2(pA0, pA1, (t + 2) * 64, dcur + 1 * 8192);
    PHASE_MID(4)
#pragma unroll
    for (int m = 0; m < 4; ++m)
#pragma unroll
      for (int n = 0; n < 4; ++n)
        acc[m][n] = __builtin_amdgcn_mfma_f32_16x16x32_bf16(av[m], b1v[n], acc[m][n], 0, 0, 0);
    PHASE_END()

    // ---- phase 4: MFMA m4-7 x kk1 (reads A-k1 hi; stage B-k1(t+2)->cur)
#pragma unroll
    for (int m = 0; m < 4; ++m) av[m] = *(const bf16x8*)(bA + PART_A1 + (m + 4) * 1024);
    if (t < KT - 2) stage2(pB0, pB1, (t + 2) * 64 + 32, dcur + 2 * 8192);
    PHASE_MID(2)
#pragma unroll
    for (int m = 0; m < 4; ++m)
#pragma unroll
      for (int n = 0; n < 4; ++n)
        acc[m + 4][n] = __builtin_amdgcn_mfma_f32_16x16x32_bf16(av[m], b1v[n], acc[m + 4][n], 0, 0, 0);
    __builtin_amdgcn_s_setprio(0);
    // counted vmcnt once per K-tile: 6 loads (3 half-tiles) stay in flight;
    // guarantees tile t+1 fully landed. Drain at KT-2 for the last tile.
    if (t < KT - 2) {
      asm volatile("s_waitcnt vmcnt(6)" ::: "memory");
    } else if (t == KT - 2) {
      asm volatile("s_waitcnt vmcnt(0)" ::: "memory");
    }
    __builtin_amdgcn_s_barrier();
  }

  // epilogue: C/D layout col=lane&15, row=(lane>>4)*4+j (m89-verified)
#pragma unroll
  for (int mm = 0; mm < 8; ++mm) {
#pragma unroll
    for (int n = 0; n < 4; ++n) {
      const int gr = row0 + wr * 128 + mm * 16 + (lane >> 4) * 4;
      const int gc = col0 + wc * 64 + n * 16 + l15;
      float* cp = C + (size_t)gr * N_DIM + gc;
#pragma unroll
      for (int j = 0; j < 4; ++j) cp[(size_t)j * N_DIM] = acc[mm][n][j];
    }
  }
}

// ---- fallback (ws too small): reg-staged f32->bf16 kernel ------------------
__global__ __launch_bounds__(256) void gemm_fb(const float* __restrict__ Af,
                                               const float* __restrict__ Bf,
                                               float* __restrict__ C) {
  __shared__ unsigned short sA[128 * 64];
  __shared__ unsigned short sB[128 * 64];
  const int tid = threadIdx.x;
  const int lane = tid & 63;
  const int wid = tid >> 6;
  const int wr = wid >> 1, wc = wid & 1;
  const int cpx = (int)gridDim.x >> 3;
  const int swz = ((int)blockIdx.x & 7) * cpx + ((int)blockIdx.x >> 3);
  const int row0 = (swz / (N_DIM / 128)) * 128;
  const int col0 = (swz % (N_DIM / 128)) * 128;
  f32x4 acc[4][4] = {};
  const int fbase = tid * 8;
  for (int kt = 0; kt < K_DIM; kt += 64) {
#pragma unroll
    for (int p = 0; p < 4; ++p) {
      const int f = fbase + p * 2048;
      const int r = f >> 6, kc = f & 63;
      const float* gA = Af + (size_t)(row0 + r) * K_DIM + kt + kc;
      const float* gB = Bf + (size_t)(col0 + r) * K_DIM + kt + kc;
      f32x4 a0 = ((const f32x4*)gA)[0], a1 = ((const f32x4*)gA)[1];
      f32x4 c0 = ((const f32x4*)gB)[0], c1 = ((const f32x4*)gB)[1];
      u16x8 va, vb;
      va[0] = f2bf(a0[0]); va[1] = f2bf(a0[1]); va[2] = f2bf(a0[2]); va[3] = f2bf(a0[3]);
      va[4] = f2bf(a1[0]); va[5] = f2bf(a1[1]); va[6] = f2bf(a1[2]); va[7] = f2bf(a1[3]);
      vb[0] = f2bf(c0[0]); vb[1] = f2bf(c0[1]); vb[2] = f2bf(c0[2]); vb[3] = f2bf(c0[3]);
      vb[4] = f2bf(c1[0]); vb[5] = f2bf(c1[1]); vb[6] = f2bf(c1[2]); vb[7] = f2bf(c1[3]);
      *(u16x8*)&sA[f] = va;
      *(u16x8*)&sB[f] = vb;
    }
    __syncthreads();
#pragma unroll
    for (int kk = 0; kk < 2; ++kk) {
      bf16x8 a[4], b[4];
#pragma unroll
      for (int m = 0; m < 4; ++m)
        a[m] = *(const bf16x8*)&sA[(wr * 64 + m * 16 + (lane & 15)) * 64 + kk * 32 + (lane >> 4) * 8];
#pragma unroll
      for (int n = 0; n < 4; ++n)
        b[n] = *(const bf16x8*)&sB[(wc * 64 + n * 16 + (lane & 15)) * 64 + kk * 32 + (lane >> 4) * 8];
#pragma unroll
      for (int m = 0; m < 4; ++m)
#pragma unroll
        for (int n = 0; n < 4; ++n)
          acc[m][n] = __builtin_amdgcn_mfma_f32_16x16x32_bf16(a[m], b[n], acc[m][n], 0, 0, 0);
    }
    __syncthreads();
  }
#pragma unroll
  for (int m = 0; m < 4; ++m)
#pragma unroll
    for (int n = 0; n < 4; ++n) {
      const int gr = row0 + wr * 64 + m * 16 + (lane >> 4) * 4;
      const int gc = col0 + wc * 64 + n * 16 + (lane & 15);
      float* cp = C + (size_t)gr * N_DIM + gc;
#pragma unroll
      for (int j = 0; j < 4; ++j) cp[(size_t)j * N_DIM] = acc[m][n][j];
    }
}

extern "C" void kernel_launch(void* const* d_in, const int* in_sizes, int n_in,
                              void* d_out, int out_size, void* d_ws, size_t ws_size,
                              hipStream_t stream) {
  const float* x = (const float*)d_in[0];  // [8192, 4096]
  const float* W = (const float*)d_in[1];  // [4096, 4096]
  float* out = (float*)d_out;              // [8192, 4096] f32

  const size_t xb_bytes = (size_t)M_DIM * K_DIM * 2;  // 64 MiB
  const size_t wb_bytes = (size_t)N_DIM * K_DIM * 2;  // 32 MiB

  if (ws_size >= xb_bytes + wb_bytes) {
    unsigned short* Xb = (unsigned short*)d_ws;
    unsigned short* Wb = (unsigned short*)((char*)d_ws + xb_bytes);
    cvt_f32_bf16<<<2048, 256, 0, stream>>>(x, Xb, (long)M_DIM * K_DIM / 8);
    cvt_f32_bf16<<<2048, 256, 0, stream>>>(W, Wb, (long)N_DIM * K_DIM / 8);
    const dim3 grid((M_DIM / BM) * (N_DIM / BN));  // 512 blocks
    gemm8p<<<grid, dim3(512), 0, stream>>>(Xb, Wb, out);
  } else {
    gemm_fb<<<dim3(2048), dim3(256), 0, stream>>>(x, W, out);
  }
}

// Round 4
// 277.945 us; speedup vs baseline: 1.5704x; 1.0068x over previous
//
#include <hip/hip_runtime.h>
#include <hip/hip_bf16.h>

// SparseLinear as dense bf16 MFMA GEMM: out[b,o] = sum_i x[b,i]*W[o,i]
// C = A * B^T, M=8192, N=4096, K=4096. bias is dead in the reference.
// 256x256 tile, BK=64, 8 waves. R4: read-ahead pipeline — ds_reads for
// phase p+1 issue BEFORE phase p's MFMA cluster (LDS pipe overlaps MFMA
// pipe), counted lgkmcnt per phase, ONE barrier per phase (4/K-tile),
// counted vmcnt at p1/p4 tops. T1 XCD swizzle + T2 LDS XOR swizzle + T5.

typedef short bf16x8 __attribute__((ext_vector_type(8)));
typedef float f32x4 __attribute__((ext_vector_type(4)));
typedef unsigned short u16x8 __attribute__((ext_vector_type(8)));

static constexpr int M_DIM = 8192;
static constexpr int N_DIM = 4096;
static constexpr int K_DIM = 4096;
static constexpr int BM = 256, BN = 256, BK = 64;
static constexpr int KT = K_DIM / BK;  // 64 K-tiles

__device__ __forceinline__ unsigned short f2bf(float f) {
  unsigned int u = __builtin_bit_cast(unsigned int, f);
  u += 0x7fffu + ((u >> 16) & 1u);
  return (unsigned short)(u >> 16);
}

__global__ void cvt_f32_bf16(const float* __restrict__ in,
                             unsigned short* __restrict__ out, long n8) {
  long i = (long)blockIdx.x * blockDim.x + threadIdx.x;
  const long stride = (long)gridDim.x * blockDim.x;
  for (; i < n8; i += stride) {
    f32x4 a = ((const f32x4*)in)[2 * i];
    f32x4 b = ((const f32x4*)in)[2 * i + 1];
    u16x8 v;
    v[0] = f2bf(a[0]); v[1] = f2bf(a[1]); v[2] = f2bf(a[2]); v[3] = f2bf(a[3]);
    v[4] = f2bf(b[0]); v[5] = f2bf(b[1]); v[6] = f2bf(b[2]); v[7] = f2bf(b[3]);
    ((u16x8*)out)[i] = v;
  }
}

// LDS part = 256 rows x 32 k bf16 = 16 KB, row stride 64 B.
// T2 swizzle (involution): byte ^= ((byte>>7)&3)<<4. XOR bits 4-5 depend on
// row bits 1-2 only -> m*1024 / part*16384 offsets are swizzle-invariant.
// parts: 0 = B,k0..31  1 = A,k0..31  2 = B,k32..63  3 = A,k32..63
#define PART_B0 0
#define PART_A0 16384
#define PART_B1 32768
#define PART_A1 49152

__device__ __forceinline__ void stage2(const unsigned short* p0,
                                       const unsigned short* p1, int k,
                                       unsigned short* dst) {
  __builtin_amdgcn_global_load_lds(
      (const __attribute__((address_space(1))) void*)(p0 + k),
      (__attribute__((address_space(3))) void*)dst, 16, 0, 0);
  __builtin_amdgcn_global_load_lds(
      (const __attribute__((address_space(1))) void*)(p1 + k),
      (__attribute__((address_space(3))) void*)(dst + 4096), 16, 0, 0);
}

#define FENCE asm volatile("" ::: "memory")
#define BAR()                        \
  do {                               \
    FENCE;                           \
    __builtin_amdgcn_s_barrier();    \
    FENCE;                           \
  } while (0)
#define LGKM(N) asm volatile("s_waitcnt lgkmcnt(" #N ")" ::: "memory")
#define VMC(N) asm volatile("s_waitcnt vmcnt(" #N ")" ::: "memory")
#define PRIO_ON()                         \
  __builtin_amdgcn_sched_barrier(0);      \
  __builtin_amdgcn_s_setprio(1)
#define PRIO_OFF() __builtin_amdgcn_s_setprio(0)

__global__ __launch_bounds__(512, 2) void gemm8p(
    const unsigned short* __restrict__ Ab, const unsigned short* __restrict__ Bb,
    float* __restrict__ C) {
  __shared__ unsigned short lds[2][4][8192];  // 128 KiB

  const int tid = threadIdx.x;
  const int lane = tid & 63;
  const int wid = tid >> 6;    // 8 waves
  const int wr = wid >> 2;     // 0..1  (M half: 128 rows)
  const int wc = wid & 3;      // 0..3  (N quarter: 64 cols)
  const int l15 = lane & 15;
  const int ks16 = (lane >> 4) << 4;

  // T1: XCD-aware bijective swizzle (512 blocks, 512 % 8 == 0)
  const int b0i = blockIdx.x;
  const int swz = (b0i & 7) * ((int)gridDim.x >> 3) + (b0i >> 3);
  const int row0 = (swz / (N_DIM / BN)) * BM;
  const int col0 = (swz % (N_DIM / BN)) * BN;

  // staging: per-thread inverse-swizzled source indices -> fixed pointers
  int r0, i0, r1, i1;
  {
    int q0 = tid * 16;
    int lo0 = q0 ^ (((q0 >> 7) & 3) << 4);
    r0 = lo0 >> 6; i0 = (lo0 & 63) >> 1;
    int q1 = tid * 16 + 8192;
    int lo1 = q1 ^ (((q1 >> 7) & 3) << 4);
    r1 = lo1 >> 6; i1 = (lo1 & 63) >> 1;
  }
  const unsigned short* pA0 = Ab + (size_t)(row0 + r0) * K_DIM + i0;
  const unsigned short* pA1 = Ab + (size_t)(row0 + r1) * K_DIM + i1;
  const unsigned short* pB0 = Bb + (size_t)(col0 + r0) * K_DIM + i0;
  const unsigned short* pB1 = Bb + (size_t)(col0 + r1) * K_DIM + i1;
  unsigned short* dst0 = &lds[0][0][0] + wid * 512;
  unsigned short* dst1 = &lds[1][0][0] + wid * 512;

  // LDS read base byte offsets (swizzled; m/part offsets fold into imms)
  int ao = ((wr * 128 + l15) * 64) + ks16;
  ao ^= ((ao >> 7) & 3) << 4;
  int bo = ((wc * 64 + l15) * 64) + ks16;
  bo ^= ((bo >> 7) & 3) << 4;

  f32x4 acc[8][4] = {};

  // prologue: tile0 all 4 parts (buf0) + tile1 parts 0,1,2 (buf1)
  stage2(pB0, pB1, 0, dst0 + 0 * 8192);
  stage2(pA0, pA1, 0, dst0 + 1 * 8192);
  stage2(pB0, pB1, 32, dst0 + 2 * 8192);
  stage2(pA0, pA1, 32, dst0 + 3 * 8192);
  stage2(pB0, pB1, 64, dst1 + 0 * 8192);
  stage2(pA0, pA1, 64, dst1 + 1 * 8192);
  stage2(pB0, pB1, 96, dst1 + 2 * 8192);
  VMC(6);  // buf0's 8 loads landed
  BAR();

  bf16x8 avA[4], avB[4], b0v[4], b1v[4];
  {
    const char* bcA = (const char*)&lds[0][0][0] + ao;
    const char* bcB = (const char*)&lds[0][0][0] + bo;
#pragma unroll
    for (int m = 0; m < 4; ++m) avA[m] = *(const bf16x8*)(bcA + PART_A0 + m * 1024);
#pragma unroll
    for (int n = 0; n < 4; ++n) b0v[n] = *(const bf16x8*)(bcB + PART_B0 + n * 1024);
  }

#pragma unroll 1
  for (int t = 0; t < KT; ++t) {
    const char* bc = (const char*)&lds[t & 1][0][0];
    const char* bn = (const char*)&lds[(t & 1) ^ 1][0][0];
    unsigned short* dcur = (t & 1) ? dst1 : dst0;
    unsigned short* dnxt = (t & 1) ? dst0 : dst1;
    const char* bcA = bc + ao;
    const char* bcB = bc + bo;
    const char* bnA = bn + ao;
    const char* bnB = bn + bo;

    // ---- p1: MFMA m0-3 k0 (avA,b0v). Read-ahead avB = A-k0 hi.
    //      Stage A-k1(t+1) -> next-buf part3.
    if (t < KT - 2) { VMC(2); } else { VMC(0); }
    BAR();
    if (t < KT - 1) stage2(pA0, pA1, (t + 1) * 64 + 32, dnxt + 3 * 8192);
#pragma unroll
    for (int m = 0; m < 4; ++m) avB[m] = *(const bf16x8*)(bcA + PART_A0 + (m + 4) * 1024);
    LGKM(4);  // avA,b0v (issued last phase) complete; avB may be in flight
    PRIO_ON();
#pragma unroll
    for (int m = 0; m < 4; ++m)
#pragma unroll
      for (int n = 0; n < 4; ++n)
        acc[m][n] = __builtin_amdgcn_mfma_f32_16x16x32_bf16(avA[m], b0v[n], acc[m][n], 0, 0, 0);
    PRIO_OFF();

    // ---- p2: MFMA m4-7 k0 (avB,b0v). Read-ahead avA = A-k1 lo, b1v = B-k1.
    //      Stage B-k0(t+2) -> cur part0.
    BAR();
    if (t < KT - 2) stage2(pB0, pB1, (t + 2) * 64, dcur + 0 * 8192);
#pragma unroll
    for (int m = 0; m < 4; ++m) avA[m] = *(const bf16x8*)(bcA + PART_A1 + m * 1024);
#pragma unroll
    for (int n = 0; n < 4; ++n) b1v[n] = *(const bf16x8*)(bcB + PART_B1 + n * 1024);
    LGKM(8);
    PRIO_ON();
#pragma unroll
    for (int m = 0; m < 4; ++m)
#pragma unroll
      for (int n = 0; n < 4; ++n)
        acc[m + 4][n] = __builtin_amdgcn_mfma_f32_16x16x32_bf16(avB[m], b0v[n], acc[m + 4][n], 0, 0, 0);
    PRIO_OFF();

    // ---- p3: MFMA m0-3 k1 (avA,b1v). Read-ahead avB = A-k1 hi.
    //      Stage A-k0(t+2) -> cur part1.
    BAR();
    if (t < KT - 2) stage2(pA0, pA1, (t + 2) * 64, dcur + 1 * 8192);
#pragma unroll
    for (int m = 0; m < 4; ++m) avB[m] = *(const bf16x8*)(bcA + PART_A1 + (m + 4) * 1024);
    LGKM(4);
    PRIO_ON();
#pragma unroll
    for (int m = 0; m < 4; ++m)
#pragma unroll
      for (int n = 0; n < 4; ++n)
        acc[m][n] = __builtin_amdgcn_mfma_f32_16x16x32_bf16(avA[m], b1v[n], acc[m][n], 0, 0, 0);
    PRIO_OFF();

    // ---- p4: MFMA m4-7 k1 (avB,b1v). Read-ahead avA = A-k0 lo(t+1),
    //      b0v = B-k0(t+1) from NEXT buffer. Stage B-k1(t+2) -> cur part2.
    if (t < KT - 2) { VMC(6); } else { VMC(0); }
    BAR();
    if (t < KT - 2) stage2(pB0, pB1, (t + 2) * 64 + 32, dcur + 2 * 8192);
    if (t < KT - 1) {
#pragma unroll
      for (int m = 0; m < 4; ++m) avA[m] = *(const bf16x8*)(bnA + PART_A0 + m * 1024);
#pragma unroll
      for (int n = 0; n < 4; ++n) b0v[n] = *(const bf16x8*)(bnB + PART_B0 + n * 1024);
      LGKM(8);
    } else {
      LGKM(0);
    }
    PRIO_ON();
#pragma unroll
    for (int m = 0; m < 4; ++m)
#pragma unroll
      for (int n = 0; n < 4; ++n)
        acc[m + 4][n] = __builtin_amdgcn_mfma_f32_16x16x32_bf16(avB[m], b1v[n], acc[m + 4][n], 0, 0, 0);
    PRIO_OFF();
  }

  // epilogue: C/D layout col=lane&15, row=(lane>>4)*4+j (m89-verified)
#pragma unroll
  for (int mm = 0; mm < 8; ++mm) {
#pragma unroll
    for (int n = 0; n < 4; ++n) {
      const int gr = row0 + wr * 128 + mm * 16 + (lane >> 4) * 4;
      const int gc = col0 + wc * 64 + n * 16 + l15;
      float* cp = C + (size_t)gr * N_DIM + gc;
#pragma unroll
      for (int j = 0; j < 4; ++j) cp[(size_t)j * N_DIM] = acc[mm][n][j];
    }
  }
}

// ---- fallback (ws too small): reg-staged f32->bf16 kernel ------------------
__global__ __launch_bounds__(256) void gemm_fb(const float* __restrict__ Af,
                                               const float* __restrict__ Bf,
                                               float* __restrict__ C) {
  __shared__ unsigned short sA[128 * 64];
  __shared__ unsigned short sB[128 * 64];
  const int tid = threadIdx.x;
  const int lane = tid & 63;
  const int wid = tid >> 6;
  const int wr = wid >> 1, wc = wid & 1;
  const int cpx = (int)gridDim.x >> 3;
  const int swz = ((int)blockIdx.x & 7) * cpx + ((int)blockIdx.x >> 3);
  const int row0 = (swz / (N_DIM / 128)) * 128;
  const int col0 = (swz % (N_DIM / 128)) * 128;
  f32x4 acc[4][4] = {};
  const int fbase = tid * 8;
  for (int kt = 0; kt < K_DIM; kt += 64) {
#pragma unroll
    for (int p = 0; p < 4; ++p) {
      const int f = fbase + p * 2048;
      const int r = f >> 6, kc = f & 63;
      const float* gA = Af + (size_t)(row0 + r) * K_DIM + kt + kc;
      const float* gB = Bf + (size_t)(col0 + r) * K_DIM + kt + kc;
      f32x4 a0 = ((const f32x4*)gA)[0], a1 = ((const f32x4*)gA)[1];
      f32x4 c0 = ((const f32x4*)gB)[0], c1 = ((const f32x4*)gB)[1];
      u16x8 va, vb;
      va[0] = f2bf(a0[0]); va[1] = f2bf(a0[1]); va[2] = f2bf(a0[2]); va[3] = f2bf(a0[3]);
      va[4] = f2bf(a1[0]); va[5] = f2bf(a1[1]); va[6] = f2bf(a1[2]); va[7] = f2bf(a1[3]);
      vb[0] = f2bf(c0[0]); vb[1] = f2bf(c0[1]); vb[2] = f2bf(c0[2]); vb[3] = f2bf(c0[3]);
      vb[4] = f2bf(c1[0]); vb[5] = f2bf(c1[1]); vb[6] = f2bf(c1[2]); vb[7] = f2bf(c1[3]);
      *(u16x8*)&sA[f] = va;
      *(u16x8*)&sB[f] = vb;
    }
    __syncthreads();
#pragma unroll
    for (int kk = 0; kk < 2; ++kk) {
      bf16x8 a[4], b[4];
#pragma unroll
      for (int m = 0; m < 4; ++m)
        a[m] = *(const bf16x8*)&sA[(wr * 64 + m * 16 + (lane & 15)) * 64 + kk * 32 + (lane >> 4) * 8];
#pragma unroll
      for (int n = 0; n < 4; ++n)
        b[n] = *(const bf16x8*)&sB[(wc * 64 + n * 16 + (lane & 15)) * 64 + kk * 32 + (lane >> 4) * 8];
#pragma unroll
      for (int m = 0; m < 4; ++m)
#pragma unroll
        for (int n = 0; n < 4; ++n)
          acc[m][n] = __builtin_amdgcn_mfma_f32_16x16x32_bf16(a[m], b[n], acc[m][n], 0, 0, 0);
    }
    __syncthreads();
  }
#pragma unroll
  for (int m = 0; m < 4; ++m)
#pragma unroll
    for (int n = 0; n < 4; ++n) {
      const int gr = row0 + wr * 64 + m * 16 + (lane >> 4) * 4;
      const int gc = col0 + wc * 64 + n * 16 + (lane & 15);
      float* cp = C + (size_t)gr * N_DIM + gc;
#pragma unroll
      for (int j = 0; j < 4; ++j) cp[(size_t)j * N_DIM] = acc[m][n][j];
    }
}

extern "C" void kernel_launch(void* const* d_in, const int* in_sizes, int n_in,
                              void* d_out, int out_size, void* d_ws, size_t ws_size,
                              hipStream_t stream) {
  const float* x = (const float*)d_in[0];  // [8192, 4096]
  const float* W = (const float*)d_in[1];  // [4096, 4096]
  float* out = (float*)d_out;              // [8192, 4096] f32

  const size_t xb_bytes = (size_t)M_DIM * K_DIM * 2;  // 64 MiB
  const size_t wb_bytes = (size_t)N_DIM * K_DIM * 2;  // 32 MiB

  if (ws_size >= xb_bytes + wb_bytes) {
    unsigned short* Xb = (unsigned short*)d_ws;
    unsigned short* Wb = (unsigned short*)((char*)d_ws + xb_bytes);
    cvt_f32_bf16<<<2048, 256, 0, stream>>>(x, Xb, (long)M_DIM * K_DIM / 8);
    cvt_f32_bf16<<<2048, 256, 0, stream>>>(W, Wb, (long)N_DIM * K_DIM / 8);
    const dim3 grid((M_DIM / BM) * (N_DIM / BN));  // 512 blocks
    gemm8p<<<grid, dim3(512), 0, stream>>>(Xb, Wb, out);
  } else {
    gemm_fb<<<dim3(2048), dim3(256), 0, stream>>>(x, W, out);
  }
}